// Round 1
// baseline (274.145 us; speedup 1.0000x reference)
//
#include <hip/hip_runtime.h>
#include <math.h>

#define NPATH 1536
#define NSEG  65
#define NB    160
#define NA    160
#define NCHUNK 4
#define PAIRS_PER_CHUNK 40   // NB / NCHUNK

// Piecewise-linear radial-MLP table: R[p](r) = r*A[seg][p] + B[seg][p]
// (per-block Wigner/norm constants pre-folded; layout permuted so that the
// main kernel's per-v loads are 128B-contiguous across lanes).
__device__ float  dg_sorted[64];
__device__ float2 dg_tbl[NSEG * NPATH];

__global__ void k_zero(float* out) {
    int i = blockIdx.x * blockDim.x + threadIdx.x;
    if (i < 2 * NA * 64) out[i] = 0.0f;
}

// thresholds t_c = -b1/W1 (W1==0 -> +inf, handled as "always/never active"),
// parallel rank sort of 64 values
__global__ void k_thresh(const float* W1, const float* b1) {
    __shared__ float tv[64];
    int c = threadIdx.x;
    float w = W1[c];
    float t = (w != 0.0f) ? (-b1[c] / w) : __builtin_inff();
    tv[c] = t;
    __syncthreads();
    float mine = tv[c];
    int rank = 0;
    for (int j = 0; j < 64; ++j) {
        float o = tv[j];
        if (o < mine || (o == mine && j < c)) rank++;
    }
    dg_sorted[rank] = mine;
}

__global__ void k_table(const float* W1, const float* b1,
                        const float* W2, const float* b2) {
    int k = blockIdx.x;   // segment id, 0..64
    __shared__ float sw[64], sb[64];
    if (threadIdx.x < 64) { sw[threadIdx.x] = W1[threadIdx.x]; sb[threadIdx.x] = b1[threadIdx.x]; }
    __syncthreads();

    // representative r strictly inside segment k
    float rep;
    float s0 = dg_sorted[0];
    if (k == 0) {
        rep = isinf(s0) ? 0.0f : (s0 - fmaxf(1.0f, fabsf(s0)));
    } else {
        float sk = (k < 64) ? dg_sorted[k] : __builtin_inff();
        float sl = dg_sorted[k - 1];
        if (isinf(sk)) rep = isinf(sl) ? 0.0f : (sl + fmaxf(1.0f, fabsf(sl)));
        else           rep = 0.5f * (sl + sk);
    }

    for (int q = threadIdx.x; q < NPATH; q += blockDim.x) {
        int p; float scl;
        if (q < 768) {
            int t = q & 255;
            int v = t >> 4, u = t & 15;
            p = (q & ~255) + (u << 4) + v;
            scl = (q < 256) ? 0.17677669529663687f   // blkA: ncA*Y0 = 1/sqrt(32)
                : (q < 512) ? 0.6266570686577502f    // blkB: ncB/sqrt3 = sqrt(4pi)/sqrt(32)
                            : 0.2558286876965162f;   // blkC: ncC/sqrt3
        } else {
            int t = q - 768;
            int v = t / 48, rm = t % 48;
            int kk = rm >> 4, u = rm & 15;
            p = 768 + ((u << 4) + v) * 3 + kk;
            scl = (kk == 0) ? 0.125f                 // blkD: ncD*Y0/sqrt3
                : (kk == 1) ? 0.3133285343288751f    // blkE: ncD/sqrt6
                            : 0.7674950309598664f;   // blkF: ncD
        }
        float A = 0.0f, B = 0.0f;
        for (int c = 0; c < 64; ++c) {
            float w = sw[c], b = sb[c];
            bool act = (w != 0.0f) ? (fmaf(w, rep, b) > 0.0f) : (b > 0.0f);
            if (act) {
                float w2 = W2[c * NPATH + p];
                A = fmaf(w, w2, A);
                B = fmaf(b, w2, B);
            }
        }
        dg_tbl[k * NPATH + q] = make_float2(scl * A, scl * (B + b2[p]));
    }
}

__global__ __launch_bounds__(256) void k_main(const float* __restrict__ feat,
                                              const float* __restrict__ geom,
                                              const float* __restrict__ mask,
                                              float* __restrict__ out) {
    int bid = blockIdx.x;
    int z     = bid / (NA * NCHUNK);
    int rem   = bid % (NA * NCHUNK);
    int a     = rem / NCHUNK;
    int chunk = rem % NCHUNK;
    int wave = threadIdx.x >> 6;
    int lane = threadIdx.x & 63;

    __shared__ float  sS[64];
    __shared__ float  sF0[4][16];
    __shared__ float4 sF1[4][16];
    __shared__ float  sAcc[4][64];

    if (threadIdx.x < 64) sS[threadIdx.x] = dg_sorted[threadIdx.x];

    const bool is0 = lane < 16;          // lanes 0..15 -> out l=0 (u=lane)
    int u, ii;                           // lanes 16..63 -> out l=1, (u, i), i fastest
    if (is0) { u = lane; ii = 0; }
    else { u = (lane - 16) / 3; ii = (lane - 16) % 3; }

    const float is30 = 0.18257418583505536f;  // 1/sqrt(30)
    const float is10 = 0.31622776601683794f;  // 1/sqrt(10)

    float acc = 0.0f;

    for (int it = 0; it < PAIRS_PER_CHUNK / 4; ++it) {
        int b = chunk * PAIRS_PER_CHUNK + it * 4 + wave;

        // stage features row for this wave's pair
        {
            float fval = feat[(z * NB + b) * 64 + lane];
            if (is0) sF0[wave][lane] = fval;
            else ((float*)&sF1[wave][(lane - 16) / 3])[(lane - 16) % 3] = fval;
        }
        __syncthreads();

        const float* g = geom + ((size_t)((z * NA + a) * NB + b)) * 3;
        float gx = g[0], gy = g[1], gz = g[2];
        float r = sqrtf(gx * gx + gy * gy + gz * gz);
        bool zr = (r == 0.0f);
        float inv = zr ? 1.0f : (1.0f / r);
        float nx = gx * inv, ny = gy * inv, nz = gz * inv;

        // segment = count(thresholds < r), binary search (wave-uniform)
        int lo = 0, hi = 64;
        #pragma unroll
        for (int step = 0; step < 6; ++step) {
            int mid = (lo + hi) >> 1;
            if (sS[mid] < r) lo = mid + 1; else hi = mid;
        }
        const float2* __restrict__ row = dg_tbl + lo * NPATH;

        // real SH (e3nn convention; l=1 order y,z,x)
        const float c1sh = 0.4886025119029199f;
        float Y1_0 = c1sh * ny, Y1_1 = c1sh * nz, Y1_2 = c1sh * nx;
        const float c21 = 1.0925484305920792f, c22 = 0.31539156525252005f, c23 = 0.5462742152960396f;
        float Y2_0 = c21 * nx * ny;
        float Y2_1 = c21 * ny * nz;
        float Y2_2 = c22 * fmaf(3.0f, nz * nz, -1.0f);
        float Y2_3 = c21 * nx * nz;
        float Y2_4 = c23 * (nx * nx - ny * ny);

        float s = 0.0f;
        if (is0) {
            #pragma unroll 4
            for (int v = 0; v < 16; ++v) {
                float2 ta = row[(v << 4) + u];          // blkA (l0<-l0 x l0)
                float2 tb = row[256 + (v << 4) + u];    // blkB (l0<-l1 x l1)
                float RA = fmaf(r, ta.x, ta.y);
                float RB = fmaf(r, tb.x, tb.y);
                float f0 = sF0[wave][v];
                float4 fj = sF1[wave][v];
                float e1 = fmaf(Y1_2, fj.z, fmaf(Y1_1, fj.y, Y1_0 * fj.x));
                s = fmaf(RA, f0, s);
                s = fmaf(RB, e1, s);
            }
            if (zr) s *= 1.4142135623730951f;  // nc zero-radius ratio sqrt(32)/4
        } else {
            float Yi = (ii == 0) ? Y1_0 : (ii == 1) ? Y1_1 : Y1_2;
            // Z row: sum_k W112[ii][j][k]*Y2[k]; e row: d(f x Y)_ii / d f_j
            float Z0, Z1, Z2, e0, e1c, e2;
            if (ii == 0) {
                Z0 = fmaf(-is30, Y2_2, -is10 * Y2_4); Z1 = is10 * Y2_1; Z2 = is10 * Y2_0;
                e0 = 0.0f; e1c = Y1_2; e2 = -Y1_1;
            } else if (ii == 1) {
                Z0 = is10 * Y2_1; Z1 = 2.0f * is30 * Y2_2; Z2 = is10 * Y2_3;
                e0 = -Y1_2; e1c = 0.0f; e2 = Y1_0;
            } else {
                Z0 = is10 * Y2_0; Z1 = is10 * Y2_3; Z2 = fmaf(-is30, Y2_2, is10 * Y2_4);
                e0 = Y1_1; e1c = -Y1_0; e2 = 0.0f;
            }
            #pragma unroll 4
            for (int v = 0; v < 16; ++v) {
                float2 tc = row[512 + (v << 4) + u];    // blkC (l1<-l0 x l1)
                const float2* dd = row + 768 + v * 48 + u;
                float2 td = dd[0];                      // blkD (l1<-l1 x l0)
                float2 te = dd[16];                     // blkE (l1<-l1 x l1, cross)
                float2 tf = dd[32];                     // blkF (l1<-l1 x l2)
                float RC = fmaf(r, tc.x, tc.y);
                float RD = fmaf(r, td.x, td.y);
                float RE = fmaf(r, te.x, te.y);
                float RF = fmaf(r, tf.x, tf.y);
                float f0 = sF0[wave][v];
                float4 fj = sF1[wave][v];
                float t0 = fmaf(RE, e0,  RF * Z0);
                float t1 = fmaf(RE, e1c, RF * Z1);
                float t2 = fmaf(RE, e2,  RF * Z2);
                float fji = (ii == 0) ? fj.x : (ii == 1) ? fj.y : fj.z;
                s = fmaf(fj.x, t0, s);
                s = fmaf(fj.y, t1, s);
                s = fmaf(fj.z, t2, s);
                s = fmaf(RD, fji, s);
                s = fmaf(RC, Yi * f0, s);
            }
            if (zr) s *= 2.0f;                 // nc zero-radius ratio 8/4
        }
        acc += s;
        __syncthreads();
    }

    sAcc[wave][lane] = acc;
    __syncthreads();
    if (threadIdx.x < 64) {
        float sum = sAcc[0][threadIdx.x] + sAcc[1][threadIdx.x]
                  + sAcc[2][threadIdx.x] + sAcc[3][threadIdx.x];
        sum *= mask[z * NA + a];  // mask broadcasts over the a-dim (a==b==160)
        atomicAdd(&out[(size_t)((z * NA + a) * 64) + threadIdx.x], sum);
    }
}

extern "C" void kernel_launch(void* const* d_in, const int* in_sizes, int n_in,
                              void* d_out, int out_size, void* d_ws, size_t ws_size,
                              hipStream_t stream) {
    (void)in_sizes; (void)n_in; (void)d_ws; (void)ws_size; (void)out_size;
    const float* feat = (const float*)d_in[0];
    const float* geom = (const float*)d_in[1];
    const float* mask = (const float*)d_in[2];
    const float* W1   = (const float*)d_in[3];
    const float* b1   = (const float*)d_in[4];
    const float* W2   = (const float*)d_in[5];
    const float* b2   = (const float*)d_in[6];
    float* out = (float*)d_out;

    k_zero  <<<(2 * NA * 64 + 255) / 256, 256, 0, stream>>>(out);
    k_thresh<<<1, 64, 0, stream>>>(W1, b1);
    k_table <<<NSEG, 256, 0, stream>>>(W1, b1, W2, b2);
    k_main  <<<2 * NA * NCHUNK, 256, 0, stream>>>(feat, geom, mask, out);
}

// Round 2
// 193.735 us; speedup vs baseline: 1.4151x; 1.4151x over previous
//
#include <hip/hip_runtime.h>
#include <math.h>

#define NPATH 1536
#define NSEG  65
#define NB    160
#define NA    160
#define CW    32   // chunks (waves) per (z,a)
#define PPW   5    // pairs per wave = NB/CW

// Piecewise-linear radial-MLP table: R[p](r) = r*A[seg][p] + B[seg][p],
// per-block Wigner/norm constants pre-folded, layout permuted so per-v loads
// are contiguous across lanes. Built incrementally: adjacent segments differ
// by exactly one ReLU crossing.
__device__ float  dg_thr[64];    // per-channel threshold -b1/W1 (inf if W1==0)
__device__ float  dg_incw[64];   // rank-sorted signed increment: sgn*W1
__device__ float  dg_incb[64];   // rank-sorted signed increment: sgn*b1
__device__ int    dg_ordc[64];   // rank-sorted channel index
__device__ float2 dg_tbl[NSEG * NPATH];

__global__ void k_init(const float* __restrict__ W1, const float* __restrict__ b1,
                       float* __restrict__ out) {
    int i = blockIdx.x * blockDim.x + threadIdx.x;
    if (i < 2 * NA * 64) out[i] = 0.0f;
    if (blockIdx.x == 0) {
        __shared__ float tv[64];
        int c = threadIdx.x;
        if (c < 64) {
            float w = W1[c];
            tv[c] = (w != 0.0f) ? (-b1[c] / w) : __builtin_inff();
        }
        __syncthreads();
        if (c < 64) {
            float mine = tv[c];
            int rank = 0;
            for (int j = 0; j < 64; ++j) {
                float o = tv[j];
                rank += (o < mine || (o == mine && j < c)) ? 1 : 0;
            }
            dg_thr[c] = mine;
            float w = W1[c], b = b1[c];
            float sgn = (w > 0.0f) ? 1.0f : ((w < 0.0f) ? -1.0f : 0.0f);
            dg_incw[rank] = sgn * w;   // crossing t_c upward: w>0 activates, w<0 deactivates
            dg_incb[rank] = sgn * b;
            dg_ordc[rank] = c;
        }
    }
}

// 6 blocks x 256 threads: one thread per layout slot q; walk 65 segments
// applying one signed increment each (instead of 65 full 64-term sums).
__global__ void k_table(const float* __restrict__ W1, const float* __restrict__ b1,
                        const float* __restrict__ W2, const float* __restrict__ b2) {
    __shared__ float sW[64], sB[64], sIw[64], sIb[64];
    __shared__ int   sC[64];
    if (threadIdx.x < 64) {
        int c = threadIdx.x;
        sW[c] = W1[c]; sB[c] = b1[c];
        sIw[c] = dg_incw[c]; sIb[c] = dg_incb[c]; sC[c] = dg_ordc[c];
    }
    __syncthreads();

    int q = blockIdx.x * 256 + threadIdx.x;   // layout index
    int p; float scl;
    if (q < 768) {
        int t = q & 255;
        int v = t >> 4, u = t & 15;
        p = (q & ~255) + (u << 4) + v;
        scl = (q < 256) ? 0.17677669529663687f   // blkA
            : (q < 512) ? 0.6266570686577502f    // blkB
                        : 0.2558286876965162f;   // blkC
    } else {
        int t = q - 768;
        int v = t / 48, rm = t % 48;
        int kk = rm >> 4, u = rm & 15;
        p = 768 + ((u << 4) + v) * 3 + kk;
        scl = (kk == 0) ? 0.125f                 // blkD
            : (kk == 1) ? 0.3133285343288751f    // blkE
                        : 0.7674950309598664f;   // blkF
    }
    float bb = b2[p];

    // segment 0: r below all finite thresholds -> active = {w<0} u {w==0 && b>0}
    float A = 0.0f, B = 0.0f;
    #pragma unroll 8
    for (int c = 0; c < 64; ++c) {
        float w = sW[c], b = sB[c];
        bool act = (w < 0.0f) || (w == 0.0f && b > 0.0f);
        if (act) {
            float w2 = W2[c * NPATH + p];
            A = fmaf(w, w2, A);
            B = fmaf(b, w2, B);
        }
    }
    dg_tbl[q] = make_float2(scl * A, scl * (B + bb));
    #pragma unroll 8
    for (int k = 1; k < NSEG; ++k) {
        int c = sC[k - 1];
        float w2 = W2[c * NPATH + p];
        A = fmaf(sIw[k - 1], w2, A);
        B = fmaf(sIb[k - 1], w2, B);
        dg_tbl[k * NPATH + q] = make_float2(scl * A, scl * (B + bb));
    }
}

__global__ __launch_bounds__(256, 4) void k_main(const float* __restrict__ feat,
                                                 const float* __restrict__ geom,
                                                 const float* __restrict__ mask,
                                                 float* __restrict__ out) {
    int wv   = threadIdx.x >> 6;
    int lane = threadIdx.x & 63;
    int gw   = blockIdx.x * 4 + wv;     // global wave id; 4 waves of a block share za
    int chunk = gw & (CW - 1);
    int za    = gw >> 5;                // z*160 + a
    int z     = za / NA;
    // za indexes mask and out directly

    __shared__ __align__(16) float sFeat[4][80];  // [0..15]=l0, [16..79]=float4-packed l1
    __shared__ float sAcc[4][64];
    float* swp = &sFeat[wv][0];

    const bool is0 = lane < 16;
    int u  = is0 ? lane : ((lane - 16) / 3);
    int i3 = is0 ? 0 : ((lane - 16) % 3);
    int waddr = is0 ? lane : (16 + u * 4 + i3);

    // per-lane table offsets within a segment row (slot0 stride 16, slots1-3 stride st1)
    int base0 = (is0 ? 0 : 512) + u;            // A | C
    int base1 = is0 ? (256 + u) : (768 + u);    // B | D
    int base2 = is0 ? (256 + u) : (768 + 16 + u); // (dup) | E
    int base3 = is0 ? (256 + u) : (768 + 32 + u); // (dup) | F
    int st1   = is0 ? 16 : 48;
    float zf  = is0 ? 1.4142135623730951f : 2.0f;  // zero-radius norm ratio
    // l1 slot-1 coefficient is the i3 basis vector (constant per lane)
    float bx = (!is0 && i3 == 0) ? 1.0f : 0.0f;
    float by = (!is0 && i3 == 1) ? 1.0f : 0.0f;
    float bz = (!is0 && i3 == 2) ? 1.0f : 0.0f;

    float thrv = dg_thr[lane];

    const float is30 = 0.18257418583505536f;  // 1/sqrt(30)
    const float is10 = 0.31622776601683794f;  // 1/sqrt(10)
    const float c1sh = 0.4886025119029199f;
    const float c21 = 1.0925484305920792f, c22 = 0.31539156525252005f, c23 = 0.5462742152960396f;

    float acc = 0.0f;

    for (int it = 0; it < PPW; ++it) {
        int b = chunk * PPW + it;

        // stage this pair's feature row into the wave's private LDS slot
        float fv = feat[((size_t)(z * NB + b)) * 64 + lane];
        swp[waddr] = fv;

        const float* g = geom + ((size_t)za * NB + b) * 3;
        float gx = g[0], gy = g[1], gz = g[2];
        float r = sqrtf(gx * gx + gy * gy + gz * gz);
        bool zr = (r == 0.0f);
        float inv = zr ? 1.0f : (1.0f / r);
        float nx = gx * inv, ny = gy * inv, nz = gz * inv;

        // segment = count(thresholds < r) via ballot (r is wave-uniform)
        unsigned long long bm = __ballot(thrv < r);
        int seg = __popcll(bm);
        const float2* __restrict__ row = dg_tbl + seg * NPATH;

        // real SH (e3nn convention; l=1 order y,z,x)
        float Y1_0 = c1sh * ny, Y1_1 = c1sh * nz, Y1_2 = c1sh * nx;
        float Y2_0 = c21 * nx * ny;
        float Y2_1 = c21 * ny * nz;
        float Y2_2 = c22 * fmaf(3.0f, nz * nz, -1.0f);
        float Y2_3 = c21 * nx * nz;
        float Y2_4 = c23 * (nx * nx - ny * ny);

        // per-lane coefficient vectors (uniform inner loop):
        //  s += R0*(c0*f0) + R1*(d1.f1) + R2*(d2.f1) + R3*(d3.f1)
        float Yi = (i3 == 0) ? Y1_0 : (i3 == 1) ? Y1_1 : Y1_2;
        float c0 = is0 ? 1.0f : Yi;
        float d1x = is0 ? Y1_0 : bx;
        float d1y = is0 ? Y1_1 : by;
        float d1z = is0 ? Y1_2 : bz;
        // e-row (cross-product couplings), zero for l0 lanes
        float d2x = is0 ? 0.0f : ((i3 == 0) ? 0.0f   : (i3 == 1) ? -Y1_2 : Y1_1);
        float d2y = is0 ? 0.0f : ((i3 == 0) ? Y1_2   : (i3 == 1) ? 0.0f  : -Y1_0);
        float d2z = is0 ? 0.0f : ((i3 == 0) ? -Y1_1  : (i3 == 1) ? Y1_0  : 0.0f);
        // Z-row (l=2 couplings), zero for l0 lanes
        float za_ = is10 * Y2_0, zb_ = is10 * Y2_1, zc_ = is10 * Y2_3;
        float zd_ = is30 * Y2_2, ze_ = is10 * Y2_4;
        float d3x = is0 ? 0.0f : ((i3 == 0) ? (-zd_ - ze_) : (i3 == 1) ? zb_ : za_);
        float d3y = is0 ? 0.0f : ((i3 == 0) ? zb_ : (i3 == 1) ? (2.0f * zd_) : zc_);
        float d3z = is0 ? 0.0f : ((i3 == 0) ? za_ : (i3 == 1) ? zc_ : (ze_ - zd_));

        int o0 = base0, o1 = base1, o2 = base2, o3 = base3;
        float s = 0.0f;
        #pragma unroll 4
        for (int v = 0; v < 16; ++v) {
            float2 t0 = row[o0];
            float2 t1 = row[o1];
            float2 t2 = row[o2];
            float2 t3 = row[o3];
            o0 += 16; o1 += st1; o2 += st1; o3 += st1;
            float R0 = fmaf(r, t0.x, t0.y);
            float R1 = fmaf(r, t1.x, t1.y);
            float R2 = fmaf(r, t2.x, t2.y);
            float R3 = fmaf(r, t3.x, t3.y);
            float f0 = swp[v];                                   // broadcast
            float4 fj = *(const float4*)&swp[16 + 4 * v];        // broadcast (w unused)
            s = fmaf(R0, c0 * f0, s);
            float dot1 = fmaf(d1z, fj.z, fmaf(d1y, fj.y, d1x * fj.x));
            s = fmaf(R1, dot1, s);
            float dot2 = fmaf(d2z, fj.z, fmaf(d2y, fj.y, d2x * fj.x));
            s = fmaf(R2, dot2, s);
            float dot3 = fmaf(d3z, fj.z, fmaf(d3y, fj.y, d3x * fj.x));
            s = fmaf(R3, dot3, s);
        }
        acc += zr ? (s * zf) : s;
    }

    sAcc[wv][lane] = acc;
    __syncthreads();
    if (threadIdx.x < 64) {
        float sum = sAcc[0][threadIdx.x] + sAcc[1][threadIdx.x]
                  + sAcc[2][threadIdx.x] + sAcc[3][threadIdx.x];
        sum *= mask[za];
        atomicAdd(&out[(size_t)za * 64 + threadIdx.x], sum);
    }
}

extern "C" void kernel_launch(void* const* d_in, const int* in_sizes, int n_in,
                              void* d_out, int out_size, void* d_ws, size_t ws_size,
                              hipStream_t stream) {
    (void)in_sizes; (void)n_in; (void)d_ws; (void)ws_size; (void)out_size;
    const float* feat = (const float*)d_in[0];
    const float* geom = (const float*)d_in[1];
    const float* mask = (const float*)d_in[2];
    const float* W1   = (const float*)d_in[3];
    const float* b1   = (const float*)d_in[4];
    const float* W2   = (const float*)d_in[5];
    const float* b2   = (const float*)d_in[6];
    float* out = (float*)d_out;

    k_init <<<80, 256, 0, stream>>>(W1, b1, out);              // 80*256 == 2*160*64
    k_table<<<6, 256, 0, stream>>>(W1, b1, W2, b2);            // 6*256 == 1536
    k_main <<<2 * NA * CW / 4, 256, 0, stream>>>(feat, geom, mask, out);
}

// Round 3
// 132.221 us; speedup vs baseline: 2.0734x; 1.4652x over previous
//
#include <hip/hip_runtime.h>
#include <math.h>

#define NPATH 1536
#define NSEG  65
#define NB    160
#define NA    160
#define CW    32   // chunks (waves) per (z,a)
#define PPW   5    // pairs per wave = NB/CW

// Piecewise-linear radial-MLP table: R[p](r) = r*slope + icpt, per-block
// Wigner/norm constants pre-folded. float4-packed, per segment 768 float4:
//   [  0..255]: (v*16+u) -> {A_s, A_i, B_s, B_i}   (l0-lane slots 0,1)
//   [256..511]: (v*16+u) -> {C_s, C_i, D_s, D_i}   (l1-lane slots 0,1)
//   [512..767]: (v*16+u) -> {E_s, E_i, F_s, F_i}   (l1-lane slots 2,3)
__device__ float  dg_thr[64];    // per-channel threshold -b1/W1 (inf if W1==0)
__device__ float  dg_incw[64];   // rank-sorted signed increment: sgn*W1
__device__ float  dg_incb[64];   // rank-sorted signed increment: sgn*b1
__device__ int    dg_ordc[64];   // rank-sorted channel index
__device__ float4 dg_tbl4[NSEG * 768];

__global__ void k_init(const float* __restrict__ W1, const float* __restrict__ b1,
                       float* __restrict__ out) {
    int i = blockIdx.x * blockDim.x + threadIdx.x;
    if (i < 2 * NA * 64) out[i] = 0.0f;
    if (blockIdx.x == 0) {
        __shared__ float tv[64];
        int c = threadIdx.x;
        if (c < 64) {
            float w = W1[c];
            tv[c] = (w != 0.0f) ? (-b1[c] / w) : __builtin_inff();
        }
        __syncthreads();
        if (c < 64) {
            float mine = tv[c];
            int rank = 0;
            for (int j = 0; j < 64; ++j) {
                float o = tv[j];
                rank += (o < mine || (o == mine && j < c)) ? 1 : 0;
            }
            dg_thr[c] = mine;
            float w = W1[c], b = b1[c];
            float sgn = (w > 0.0f) ? 1.0f : ((w < 0.0f) ? -1.0f : 0.0f);
            dg_incw[rank] = sgn * w;   // crossing t_c upward: w>0 activates, w<0 deactivates
            dg_incb[rank] = sgn * b;
            dg_ordc[rank] = c;
        }
    }
}

// 12 blocks x 128 threads. Stage a 64x128 W2 tile in LDS (coalesced), then
// each thread owns one path p: seg-0 masked sum + 64 rank-ordered signed
// increments, all reading LDS. Stores go to the float4-packed layout.
__global__ void k_table(const float* __restrict__ W1, const float* __restrict__ b1,
                        const float* __restrict__ W2, const float* __restrict__ b2) {
    __shared__ float sW2[64 * 128];
    int tid = threadIdx.x;
    int p0  = blockIdx.x * 128;
    for (int c = 0; c < 64; ++c)
        sW2[c * 128 + tid] = W2[c * NPATH + p0 + tid];
    __syncthreads();

    int p = p0 + tid;
    int idx, half; float scl;
    if (p < 768) {
        int u = (p >> 4) & 15, v = p & 15;
        if (p < 256)      { idx = v * 16 + u;       half = 0; scl = 0.17677669529663687f; } // A
        else if (p < 512) { idx = v * 16 + u;       half = 1; scl = 0.6266570686577502f;  } // B
        else              { idx = 256 + v * 16 + u; half = 0; scl = 0.2558286876965162f;  } // C
    } else {
        int m = (p - 768) / 3, kk = (p - 768) % 3;
        int u = m >> 4, v = m & 15;
        if (kk == 0)      { idx = 256 + v * 16 + u; half = 1; scl = 0.125f;               } // D
        else if (kk == 1) { idx = 512 + v * 16 + u; half = 0; scl = 0.3133285343288751f;  } // E
        else              { idx = 512 + v * 16 + u; half = 1; scl = 0.7674950309598664f;  } // F
    }
    float bb = b2[p];
    float2* dst = (float2*)dg_tbl4;
    int doff = idx * 2 + half;      // float2 index within a segment row (row=1536 f2)

    // segment 0: r below all finite thresholds -> active = {w<0} u {w==0 && b>0}
    float A = 0.0f, B = 0.0f;
    #pragma unroll 8
    for (int c = 0; c < 64; ++c) {
        float w = W1[c], b = b1[c];
        bool act = (w < 0.0f) || (w == 0.0f && b > 0.0f);
        if (act) {
            float w2 = sW2[c * 128 + tid];
            A = fmaf(w, w2, A);
            B = fmaf(b, w2, B);
        }
    }
    dst[doff] = make_float2(scl * A, scl * (B + bb));
    #pragma unroll 8
    for (int k = 1; k < NSEG; ++k) {
        int c = dg_ordc[k - 1];
        float w2 = sW2[c * 128 + tid];
        A = fmaf(dg_incw[k - 1], w2, A);
        B = fmaf(dg_incb[k - 1], w2, B);
        dst[k * 1536 + doff] = make_float2(scl * A, scl * (B + bb));
    }
}

__global__ __launch_bounds__(256, 4) void k_main(const float* __restrict__ feat,
                                                 const float* __restrict__ geom,
                                                 const float* __restrict__ mask,
                                                 float* __restrict__ out) {
    int wv   = threadIdx.x >> 6;
    int lane = threadIdx.x & 63;
    int gw   = blockIdx.x * 4 + wv;     // 4 waves of a block share za
    int chunk = gw & (CW - 1);
    int za    = gw >> 5;                // z*160 + a
    int z     = za / NA;

    __shared__ __align__(16) float sFeat[4][PPW][80]; // [0..15]=l0, [16..79]=f4-packed l1
    __shared__ float sAcc[4][64];
    float* swp = &sFeat[wv][0][0];

    const bool is0 = lane < 16;
    int u  = is0 ? lane : ((lane - 16) / 3);
    int i3 = is0 ? 0 : ((lane - 16) % 3);
    int waddr = is0 ? lane : (16 + u * 4 + i3);

    int o_base = (is0 ? 0 : 256) + u;   // first float4 slot within segment row
    int sec    = is0 ? 0 : 256;         // second load offset (l0: same addr, L1 hit)
    float zfl  = is0 ? 1.4142135623730951f : 2.0f;  // zero-radius norm ratio
    float bx = (!is0 && i3 == 0) ? 1.0f : 0.0f;
    float by = (!is0 && i3 == 1) ? 1.0f : 0.0f;
    float bz = (!is0 && i3 == 2) ? 1.0f : 0.0f;

    float thrv = dg_thr[lane];

    const float is30 = 0.18257418583505536f;  // 1/sqrt(30)
    const float is10 = 0.31622776601683794f;  // 1/sqrt(10)
    const float c1sh = 0.4886025119029199f;
    const float c21 = 1.0925484305920792f, c22 = 0.31539156525252005f, c23 = 0.5462742152960396f;

    // ---- stage all PPW feature rows (wave-private LDS, no barrier) ----
    int b0 = chunk * PPW;
    #pragma unroll
    for (int it = 0; it < PPW; ++it) {
        float fv = feat[((size_t)(z * NB + b0 + it)) * 64 + lane];
        sFeat[wv][it][waddr] = fv;
    }

    // ---- precompute geometry/segment for all PPW pairs ----
    float rr[PPW], nxa[PPW], nya[PPW], nza[PPW], zfa[PPW];
    int rowo[PPW];
    #pragma unroll
    for (int it = 0; it < PPW; ++it) {
        const float* g = geom + ((size_t)za * NB + b0 + it) * 3;
        float gx = g[0], gy = g[1], gz = g[2];
        float r = sqrtf(gx * gx + gy * gy + gz * gz);
        bool zr = (r == 0.0f);
        float inv = zr ? 1.0f : (1.0f / r);
        nxa[it] = gx * inv; nya[it] = gy * inv; nza[it] = gz * inv;
        rr[it] = r;
        zfa[it] = zr ? zfl : 1.0f;
        unsigned long long bm = __ballot(thrv < r);
        rowo[it] = __popcll(bm) * 768;
    }

    float acc = 0.0f;

    #pragma unroll
    for (int it = 0; it < PPW; ++it) {
        float r = rr[it];
        float nx = nxa[it], ny = nya[it], nz = nza[it];

        // real SH (e3nn convention; l=1 order y,z,x)
        float Y1_0 = c1sh * ny, Y1_1 = c1sh * nz, Y1_2 = c1sh * nx;
        float Y2_0 = c21 * nx * ny;
        float Y2_1 = c21 * ny * nz;
        float Y2_2 = c22 * fmaf(3.0f, nz * nz, -1.0f);
        float Y2_3 = c21 * nx * nz;
        float Y2_4 = c23 * (nx * nx - ny * ny);

        // per-lane coefficient vectors (uniform inner loop):
        //  s += R0*(c0*f0) + R1*(d1.f1) + R2*(d2.f1) + R3*(d3.f1)
        float Yi = (i3 == 0) ? Y1_0 : (i3 == 1) ? Y1_1 : Y1_2;
        float c0 = is0 ? 1.0f : Yi;
        float d1x = is0 ? Y1_0 : bx;
        float d1y = is0 ? Y1_1 : by;
        float d1z = is0 ? Y1_2 : bz;
        float d2x = is0 ? 0.0f : ((i3 == 0) ? 0.0f   : (i3 == 1) ? -Y1_2 : Y1_1);
        float d2y = is0 ? 0.0f : ((i3 == 0) ? Y1_2   : (i3 == 1) ? 0.0f  : -Y1_0);
        float d2z = is0 ? 0.0f : ((i3 == 0) ? -Y1_1  : (i3 == 1) ? Y1_0  : 0.0f);
        float za_ = is10 * Y2_0, zb_ = is10 * Y2_1, zc_ = is10 * Y2_3;
        float zd_ = is30 * Y2_2, ze_ = is10 * Y2_4;
        float d3x = is0 ? 0.0f : ((i3 == 0) ? (-zd_ - ze_) : (i3 == 1) ? zb_ : za_);
        float d3y = is0 ? 0.0f : ((i3 == 0) ? zb_ : (i3 == 1) ? (2.0f * zd_) : zc_);
        float d3z = is0 ? 0.0f : ((i3 == 0) ? za_ : (i3 == 1) ? zc_ : (ze_ - zd_));

        const float4* __restrict__ row = dg_tbl4 + rowo[it];
        const float*  sp = &sFeat[wv][it][0];
        int o = o_base;
        float s = 0.0f;
        #pragma unroll 8
        for (int v = 0; v < 16; ++v) {
            float4 t01 = row[o];
            float4 t23 = row[o + sec];
            o += 16;
            float R0 = fmaf(r, t01.x, t01.y);
            float R1 = fmaf(r, t01.z, t01.w);
            float R2 = fmaf(r, t23.x, t23.y);
            float R3 = fmaf(r, t23.z, t23.w);
            float f0 = sp[v];                                 // LDS broadcast
            float4 fj = *(const float4*)&sp[16 + 4 * v];      // LDS broadcast (w unused)
            s = fmaf(R0, c0 * f0, s);
            float dot1 = fmaf(d1z, fj.z, fmaf(d1y, fj.y, d1x * fj.x));
            s = fmaf(R1, dot1, s);
            float dot2 = fmaf(d2z, fj.z, fmaf(d2y, fj.y, d2x * fj.x));
            s = fmaf(R2, dot2, s);
            float dot3 = fmaf(d3z, fj.z, fmaf(d3y, fj.y, d3x * fj.x));
            s = fmaf(R3, dot3, s);
        }
        acc = fmaf(s, zfa[it], acc);
    }

    sAcc[wv][lane] = acc;
    __syncthreads();
    if (threadIdx.x < 64) {
        float sum = sAcc[0][threadIdx.x] + sAcc[1][threadIdx.x]
                  + sAcc[2][threadIdx.x] + sAcc[3][threadIdx.x];
        sum *= mask[za];
        atomicAdd(&out[(size_t)za * 64 + threadIdx.x], sum);
    }
}

extern "C" void kernel_launch(void* const* d_in, const int* in_sizes, int n_in,
                              void* d_out, int out_size, void* d_ws, size_t ws_size,
                              hipStream_t stream) {
    (void)in_sizes; (void)n_in; (void)d_ws; (void)ws_size; (void)out_size;
    const float* feat = (const float*)d_in[0];
    const float* geom = (const float*)d_in[1];
    const float* mask = (const float*)d_in[2];
    const float* W1   = (const float*)d_in[3];
    const float* b1   = (const float*)d_in[4];
    const float* W2   = (const float*)d_in[5];
    const float* b2   = (const float*)d_in[6];
    float* out = (float*)d_out;

    k_init <<<80, 256, 0, stream>>>(W1, b1, out);        // 80*256 == 2*160*64
    k_table<<<12, 128, 0, stream>>>(W1, b1, W2, b2);     // 12*128 == 1536
    k_main <<<2 * NA * CW / 4, 256, 0, stream>>>(feat, geom, mask, out);
}